// Round 13
// baseline (179.742 us; speedup 1.0000x reference)
//
#include <hip/hip_runtime.h>
#include <hip/hip_bf16.h>

#define TT 2048

typedef __attribute__((ext_vector_type(8))) short bf16x8;
typedef __attribute__((ext_vector_type(4))) float f32x4;
typedef __attribute__((ext_vector_type(16))) float f32x16;
typedef __attribute__((ext_vector_type(2))) int i32x2;

__device__ __forceinline__ short f2b(float f) {
  union { float f; unsigned u; } a; a.f = f;
  unsigned r = a.u + 0x7fffu + ((a.u >> 16) & 1u);
  return (short)(r >> 16);
}
__device__ __forceinline__ unsigned cvtpk(float lo, float hi) {
  unsigned r;
  asm("v_cvt_pk_bf16_f32 %0, %1, %2" : "=v"(r) : "v"(lo), "v"(hi));
  return r;
}
__device__ __forceinline__ float max3f(float a, float b, float c) {
  float d;
  asm("v_max3_f32 %0, %1, %2, %3" : "=v"(d) : "v"(a), "v"(b), "v"(c));
  return d;
}
__device__ __forceinline__ float ex2(float x) {
#if __has_builtin(__builtin_amdgcn_exp2f)
  return __builtin_amdgcn_exp2f(x);
#else
  return exp2f(x);
#endif
}
// async global->LDS, 16B per lane; lds dest = wave-uniform base + lane*16
__device__ __forceinline__ void gll16(const void* g, void* l) {
  __builtin_amdgcn_global_load_lds(
      (const __attribute__((address_space(1))) unsigned int*)g,
      (__attribute__((address_space(3))) unsigned int*)l, 16, 0, 0);
}
// exchange high-32 lanes of a with low-32 lanes of b
__device__ __forceinline__ void swap_halves(unsigned &a, unsigned &b, bool hi) {
#if __has_builtin(__builtin_amdgcn_permlane32_swap)
  i32x2 r = __builtin_amdgcn_permlane32_swap((int)a, (int)b, false, false);
  a = (unsigned)r[0]; b = (unsigned)r[1];
#else
  unsigned as = (unsigned)__shfl_xor((int)a, 32);
  unsigned bs = (unsigned)__shfl_xor((int)b, 32);
  unsigned na = hi ? bs : a;
  unsigned nb = hi ? b : as;
  a = na; b = nb;
#endif
}

// 16 f32 P-values (one 32-row S^T fragment) -> two PV A-frags
__device__ __forceinline__ void p_to_frags(const f32x16 p, bool hi, bf16x8* f0, bf16x8* f1) {
  unsigned A[4][2];
#pragma unroll
  for (int u = 0; u < 4; ++u)
#pragma unroll
    for (int c = 0; c < 2; ++c)
      A[u][c] = cvtpk(p[4 * u + 2 * c], p[4 * u + 2 * c + 1]);
  swap_halves(A[0][0], A[1][0], hi);
  swap_halves(A[0][1], A[1][1], hi);
  swap_halves(A[2][0], A[3][0], hi);
  swap_halves(A[2][1], A[3][1], hi);
  union { unsigned u[4]; bf16x8 v; } r0, r1;
  r0.u[0] = A[0][0]; r0.u[1] = A[0][1]; r0.u[2] = A[1][0]; r0.u[3] = A[1][1];
  r1.u[0] = A[2][0]; r1.u[1] = A[2][1]; r1.u[2] = A[3][0]; r1.u[3] = A[3][1];
  *f0 = r0.v; *f1 = r1.v;
}

// swizzled LDS access, 128B rows: byte col ^ ((row&7)<<4)
__device__ __forceinline__ bf16x8 lds16(const short* base, int row, int cb) {
  return *reinterpret_cast<const bf16x8*>(
      reinterpret_cast<const char*>(base) + row * 128 + (cb ^ ((row & 7) << 4)));
}

// fused: LayerNorm (blocks 0..8191) + weight transpose-cast (8192..8447) +
// RoPE table (8448..8703)
__global__ __launch_bounds__(256) void prepln_kernel(const float* __restrict__ x,
                                                     const float* __restrict__ lnw,
                                                     const float* __restrict__ lnb,
                                                     short* __restrict__ h,
                                                     const float* __restrict__ w_qkv,
                                                     short* __restrict__ wqkvT,
                                                     const float* __restrict__ w_o,
                                                     short* __restrict__ woT,
                                                     float2* __restrict__ tab) {
  __shared__ float t[64][65];
  const int id = blockIdx.x;
  const int tid = threadIdx.x;
  if (id < 8192) {
    // LayerNorm: 2 rows/block, float4 loads
    const int row = id * 2 + (tid >> 7);
    const int c = tid & 127;
    const float4 v = *reinterpret_cast<const float4*>(x + (size_t)row * 512 + c * 4);
    float s = (v.x + v.y) + (v.z + v.w);
    float sq = (v.x * v.x + v.y * v.y) + (v.z * v.z + v.w * v.w);
    for (int off = 1; off < 64; off <<= 1) { s += __shfl_xor(s, off); sq += __shfl_xor(sq, off); }
    __shared__ float red[8];
    const int wv = tid >> 6;
    if ((tid & 63) == 0) { red[wv] = s; red[wv + 4] = sq; }
    __syncthreads();
    const int rb = (tid >> 7) ? 2 : 0;
    s = red[rb] + red[rb + 1];
    sq = red[rb + 4] + red[rb + 5];
    const float mu = s * (1.0f / 512.0f);
    const float var = sq * (1.0f / 512.0f) - mu * mu;
    const float inv = rsqrtf(var + 1e-5f);
    const float4 wv4 = *reinterpret_cast<const float4*>(lnw + c * 4);
    const float4 bv4 = *reinterpret_cast<const float4*>(lnb + c * 4);
    const float h0 = (v.x - mu) * inv * wv4.x + bv4.x;
    const float h1 = (v.y - mu) * inv * wv4.y + bv4.y;
    const float h2 = (v.z - mu) * inv * wv4.z + bv4.z;
    const float h3 = (v.w - mu) * inv * wv4.w + bv4.w;
    uint2 u;
    u.x = (unsigned)(unsigned short)f2b(h0) | ((unsigned)(unsigned short)f2b(h1) << 16);
    u.y = (unsigned)(unsigned short)f2b(h2) | ((unsigned)(unsigned short)f2b(h3) << 16);
    *reinterpret_cast<uint2*>(h + (size_t)row * 512 + c * 4) = u;
  } else if (id < 8448) {
    const int id2 = id - 8192;
    const float* src; short* dst; int N, n0, k0;
    if (id2 < 192) { src = w_qkv; dst = wqkvT; N = 1536; n0 = (id2 % 24) * 64; k0 = (id2 / 24) * 64; }
    else { const int i2 = id2 - 192; src = w_o; dst = woT; N = 512; n0 = (i2 & 7) * 64; k0 = (i2 >> 3) * 64; }
    const int c = tid & 63, r4 = tid >> 6;
#pragma unroll
    for (int i = 0; i < 16; ++i) {
      const int r = i * 4 + r4;
      t[r][c] = src[(size_t)(k0 + r) * N + n0 + c];
    }
    __syncthreads();
#pragma unroll
    for (int i = 0; i < 16; ++i) {
      const int r = i * 4 + r4;
      dst[(size_t)(n0 + r) * 512 + k0 + c] = f2b(t[c][r]);
    }
  } else {
    const int idx = (id - 8448) * 256 + tid;  // 65536
    const int i = idx & 31, tt = idx >> 5;
    const float inv_freq = __expf(-(float)i * (9.210340371976184f / 32.0f));
    float sv, cv;
    sincosf((float)tt * inv_freq, &sv, &cv);
    tab[idx] = make_float2(cv, sv);
  }
}

// 128x128 tile GEMM via global_load_lds, both-sides-swizzled LDS [128][64],
// T4 pipeline (counted vmcnt + raw barriers).
// Orientation: q/k blocks and EPI=1 use SWAPPED operands (C^T) so each lane
// holds 4 consecutive OUTPUT-COLUMNS -> packed 8B/16B stores. v blocks use
// normal orientation (lane holds 4 consecutive t) -> packed 8B stores to v^T.
template <int EPI>
__global__ __launch_bounds__(256) void gemm128_kernel(const short* __restrict__ A,
                                                      const short* __restrict__ Bt,
                                                      const float* __restrict__ bias,
                                                      const float2* __restrict__ tab,
                                                      void* __restrict__ o0,
                                                      void* __restrict__ o1,
                                                      void* __restrict__ o2) {
  __shared__ short As[2][128 * 64];
  __shared__ short Bs[2][128 * 64];
  const int tid = threadIdx.x;
  const int lane = tid & 63, wave = tid >> 6;
  const int lr = lane & 15, lg = lane >> 4;
  const int wm = wave >> 1, wn = wave & 1;
  const int m0 = blockIdx.x * 128, n0 = blockIdx.y * 128;
  const bool swp = (EPI == 1) || (n0 < 1024);   // q/k + O-proj: swapped orientation

  const int swz_col = ((lane & 7) ^ ((lane >> 3) & 7)) * 8;
  const short* Ag = A + (size_t)(m0 + wave * 32 + (lane >> 3)) * 512 + swz_col;
  const short* Bg = Bt + (size_t)(n0 + wave * 32 + (lane >> 3)) * 512 + swz_col;

  f32x4 acc[4][4] = {};

  auto stage = [&](int kk, int buf) {
#pragma unroll
    for (int i = 0; i < 4; ++i) {
      gll16(Ag + (size_t)i * 8 * 512 + kk * 64, &As[buf][(wave * 32 + i * 8) * 64]);
      gll16(Bg + (size_t)i * 8 * 512 + kk * 64, &Bs[buf][(wave * 32 + i * 8) * 64]);
    }
  };
  auto compute = [&](int buf) {
#pragma unroll
    for (int ks = 0; ks < 2; ++ks) {
      bf16x8 af[4], bfr[4];
#pragma unroll
      for (int m = 0; m < 4; ++m)
        af[m] = lds16(As[buf], wm * 64 + m * 16 + lr, ks * 64 + lg * 16);
#pragma unroll
      for (int n = 0; n < 4; ++n)
        bfr[n] = lds16(Bs[buf], wn * 64 + n * 16 + lr, ks * 64 + lg * 16);
      if (swp) {
#pragma unroll
        for (int p = 0; p < 4; ++p)
#pragma unroll
          for (int q = 0; q < 4; ++q)
            acc[p][q] = __builtin_amdgcn_mfma_f32_16x16x32_bf16(bfr[p], af[q], acc[p][q], 0, 0, 0);
      } else {
#pragma unroll
        for (int m = 0; m < 4; ++m)
#pragma unroll
          for (int n = 0; n < 4; ++n)
            acc[m][n] = __builtin_amdgcn_mfma_f32_16x16x32_bf16(af[m], bfr[n], acc[m][n], 0, 0, 0);
      }
    }
  };

  stage(0, 0);
  for (int kk = 0; kk < 7; ++kk) {
    stage(kk + 1, (kk + 1) & 1);
    // wait only tile kk's 8 glls (kk+1's 8 stay in flight across the barrier)
    asm volatile("s_waitcnt vmcnt(8)" ::: "memory");
    __builtin_amdgcn_s_barrier();
    __builtin_amdgcn_sched_barrier(0);
    compute(kk & 1);
    __builtin_amdgcn_s_barrier();  // WAR: all waves done reading buf kk&1
  }
  asm volatile("s_waitcnt vmcnt(0)" ::: "memory");
  __builtin_amdgcn_s_barrier();
  __builtin_amdgcn_sched_barrier(0);
  compute(1);  // tile 7

  if (EPI == 1) {
    float* outp = (float*)o0;
#pragma unroll
    for (int p = 0; p < 4; ++p) {
      const int col0 = n0 + wn * 64 + p * 16 + lg * 4;
      const float4 bv = *reinterpret_cast<const float4*>(bias + col0);
#pragma unroll
      for (int q = 0; q < 4; ++q) {
        const int row = m0 + wm * 64 + q * 16 + lr;
        float4 v;
        v.x = acc[p][q][0] + bv.x;
        v.y = acc[p][q][1] + bv.y;
        v.z = acc[p][q][2] + bv.z;
        v.w = acc[p][q][3] + bv.w;
        *reinterpret_cast<float4*>(outp + (size_t)row * 512 + col0) = v;
      }
    }
  } else {
    const int base = n0 + wn * 64;             // wave-uniform head window
    const int which = n0 >> 9;                 // block-uniform: 0=q 1=k 2=v
    const int hh = (base & 511) >> 6;
    const int bb = m0 >> 11;                   // block-uniform batch
    const int tl = m0 & 2047;
    const size_t bhT = (size_t)(bb * 8 + hh) * TT;
    if (which < 2) {
      // swapped orientation: lane holds d = p*16+lg*4+j at t = q*16+lr
      short* dstb = (short*)(which == 0 ? o0 : o1);
      const float QS = 0.125f * 1.4426950408889634f;
#pragma unroll
      for (int q = 0; q < 4; ++q) {
        const int t = tl + wm * 64 + q * 16 + lr;
        short* rowp = dstb + (bhT + t) * 64;
        const float2* tabr = tab + t * 32;
#pragma unroll
        for (int pp = 0; pp < 2; ++pp) {
          float r_lo[4], r_hi[4];
#pragma unroll
          for (int j = 0; j < 4; ++j) {
            const int i = pp * 16 + lg * 4 + j;  // d & 31
            const float2 cs = tabr[i];
            const float vlo = acc[pp][q][j] + bias[base + i];
            const float vhi = acc[pp + 2][q][j] + bias[base + 32 + i];
            float rl = vlo * cs.x - vhi * cs.y;
            float rh = vhi * cs.x + vlo * cs.y;
            if (which == 0) { rl *= QS; rh *= QS; }
            r_lo[j] = rl; r_hi[j] = rh;
          }
          uint2 plo, phi;
          plo.x = cvtpk(r_lo[0], r_lo[1]); plo.y = cvtpk(r_lo[2], r_lo[3]);
          phi.x = cvtpk(r_hi[0], r_hi[1]); phi.y = cvtpk(r_hi[2], r_hi[3]);
          *reinterpret_cast<uint2*>(rowp + pp * 16 + lg * 4) = plo;
          *reinterpret_cast<uint2*>(rowp + (pp + 2) * 16 + lg * 4) = phi;
        }
      }
    } else {
      // normal orientation: lane holds 4 consecutive t at fixed d -> v^T [d][t]
      short* vtp = (short*)o2;
#pragma unroll
      for (int n = 0; n < 4; ++n) {
        const int d = n * 16 + lr;
        const float bv = bias[base + d];
#pragma unroll
        for (int m = 0; m < 4; ++m) {
          const int t0 = tl + wm * 64 + m * 16 + lg * 4;
          uint2 pv;
          pv.x = cvtpk(acc[m][n][0] + bv, acc[m][n][1] + bv);
          pv.y = cvtpk(acc[m][n][2] + bv, acc[m][n][3] + bv);
          *reinterpret_cast<uint2*>(vtp + ((size_t)(bb * 8 + hh) * 64 + d) * TT + t0) = pv;
        }
      }
    }
  }
}

// Flash attention, swapped-QK^T 32x32x16, exp2 softmax, gll-staged pipeline.
// 8 waves x 32 q-rows = 256 q-rows/block. Depth-2: 2 K-tiles per barrier,
// 4-deep K/V LDS rings. [round-11 proven structure — unchanged]
__global__ __launch_bounds__(512) void attn_kernel(const short* __restrict__ q,
                                                   const short* __restrict__ k,
                                                   const short* __restrict__ vt,
                                                   const unsigned char* __restrict__ mask,
                                                   short* __restrict__ o) {
  __shared__ short Ks[4][64 * 64];
  __shared__ short Vs[4][64 * 64];
  __shared__ float psc[8][32];
  const int tid = threadIdx.x;
  const int lane = tid & 63, wave = tid >> 6;  // wave 0..7
  const int l31 = lane & 31, g = lane >> 5;
  const bool hi = (g != 0);
  // bijective XCD swizzle: 512 blocks, 8 XCDs -> 8 q-tiles of one bh per XCD
  const int nb = (blockIdx.x & 7) * 64 + (blockIdx.x >> 3);
  const int bh = nb >> 3, qt = nb & 7;
  const int bb = bh >> 3, hh = bh & 7;
  const int q0 = qt * 256 + wave * 32;
  const size_t bhT = (size_t)bh * TT;
  const unsigned char* maskb = mask + (size_t)bb * TT;

  // whole-row mask flag (hoisted)
  unsigned mor = 0;
  const unsigned* mw = (const unsigned*)maskb;
#pragma unroll
  for (int i = 0; i < 8; ++i) mor |= mw[lane + 64 * i];
  const bool masked = __any((int)(mor != 0));

  // Q as B-operand frags
  bf16x8 qf[4];
#pragma unroll
  for (int ds = 0; ds < 4; ++ds)
    qf[ds] = *reinterpret_cast<const bf16x8*>(q + (bhT + q0 + l31) * 64 + ds * 16 + g * 8);

  f32x16 oa0 = {}, oa1 = {};
  float m_run = 0.0f, l_run = 0.0f;

  // gll staging: wave w stages K rows [w*8, +8) and V d-rows [w*8, +8)
  const int swz_col = ((lane & 7) ^ ((lane >> 3) & 7)) * 8;
  const int r0 = wave * 8;
  const short* kg0 = k + (bhT + r0 + (lane >> 3)) * 64 + swz_col;
  const short* vg0 = vt + ((size_t)bh * 64 + r0 + (lane >> 3)) * TT + swz_col;

  auto stage = [&](int kt, int buf) {
    gll16(kg0 + (size_t)kt * 4096, &Ks[buf][r0 * 64]);
    gll16(vg0 + (size_t)kt * 64,   &Vs[buf][r0 * 64]);
  };

  auto tile = [&](int kt, const short* Kc, const short* Vc) {
    // S^T = K Q^T
    f32x16 s0 = {}, s1 = {};
    __builtin_amdgcn_s_setprio(1);
#pragma unroll
    for (int ds = 0; ds < 4; ++ds) {
      const int cb = ds * 32 + g * 16;
      const bf16x8 ka0 = lds16(Kc, l31, cb);
      const bf16x8 ka1 = lds16(Kc, 32 + l31, cb);
      s0 = __builtin_amdgcn_mfma_f32_32x32x16_bf16(ka0, qf[ds], s0, 0, 0, 0);
      s1 = __builtin_amdgcn_mfma_f32_32x32x16_bf16(ka1, qf[ds], s1, 0, 0, 0);
    }
    __builtin_amdgcn_s_setprio(0);

    if (masked) {
#pragma unroll
      for (int r = 0; r < 16; ++r) {
        const int kk = (r & 3) + 8 * (r >> 2) + 4 * g;
        if (maskb[kt * 64 + kk]) s0[r] += -1e30f;
        if (maskb[kt * 64 + 32 + kk]) s1[r] += -1e30f;
      }
    }

    // row max over 64 keys: max3 tree + cross-half
    float b8[8];
#pragma unroll
    for (int i = 0; i < 8; ++i) b8[i] = max3f(s0[i], s0[i + 8], s1[i]);
    float c4[4];
#pragma unroll
    for (int i = 0; i < 4; ++i) c4[i] = fmaxf(s1[8 + i], s1[12 + i]);
    const float d0 = max3f(b8[0], b8[1], b8[2]);
    const float d1 = max3f(b8[3], b8[4], b8[5]);
    const float d2 = max3f(b8[6], b8[7], c4[0]);
    const float d3 = max3f(c4[1], c4[2], c4[3]);
    const float mx = fmaxf(max3f(d0, d1, d2), d3);
    const float pmax = fmaxf(mx, __shfl_xor(mx, 32));

    if (kt == 0) {
      m_run = pmax;
    } else if (!__all((int)(pmax - m_run <= 8.0f))) {
      const float nm = fmaxf(m_run, pmax);
      const float sc = ex2(m_run - nm);
      m_run = nm;
      l_run *= sc;
      if (lane < 32) psc[wave][l31] = sc;
      asm volatile("s_waitcnt lgkmcnt(0)" ::: "memory");
#pragma unroll
      for (int r = 0; r < 16; ++r) {
        const float s = psc[wave][(r & 3) + 8 * (r >> 2) + 4 * g];
        oa0[r] *= s; oa1[r] *= s;
      }
    }

    // P = exp2(S - m) in place
#pragma unroll
    for (int i = 0; i < 16; ++i) { s0[i] = ex2(s0[i] - m_run); s1[i] = ex2(s1[i] - m_run); }

    // row sum (pairwise tree)
    float a8[8];
#pragma unroll
    for (int i = 0; i < 8; ++i) a8[i] = (s0[i] + s0[i + 8]) + (s1[i] + s1[i + 8]);
    const float e0 = (a8[0] + a8[1]) + (a8[2] + a8[3]);
    const float e1 = (a8[4] + a8[5]) + (a8[6] + a8[7]);
    const float rsum = e0 + e1;
    l_run += rsum + __shfl_xor(rsum, 32);

    // P -> bf16 A-frags in-register
    bf16x8 pa[4];
    p_to_frags(s0, hi, &pa[0], &pa[1]);
    p_to_frags(s1, hi, &pa[2], &pa[3]);

    // O += P V
    __builtin_amdgcn_s_setprio(1);
#pragma unroll
    for (int ks = 0; ks < 4; ++ks) {
      const int cb = ks * 32 + g * 16;
      const bf16x8 vb0 = lds16(Vc, l31, cb);
      const bf16x8 vb1 = lds16(Vc, 32 + l31, cb);
      oa0 = __builtin_amdgcn_mfma_f32_32x32x16_bf16(pa[ks], vb0, oa0, 0, 0, 0);
      oa1 = __builtin_amdgcn_mfma_f32_32x32x16_bf16(pa[ks], vb1, oa1, 0, 0, 0);
    }
    __builtin_amdgcn_s_setprio(0);
  };

  // prologue: stage tiles 0 and 1
  stage(0, 0);
  stage(1, 1);
  __syncthreads();

  for (int kt = 0; kt < TT / 64; kt += 2) {
    if (kt + 2 < TT / 64) stage(kt + 2, (kt + 2) & 3);
    if (kt + 3 < TT / 64) stage(kt + 3, (kt + 3) & 3);
    tile(kt,     Ks[kt & 3],       Vs[kt & 3]);
    tile(kt + 1, Ks[(kt + 1) & 3], Vs[(kt + 1) & 3]);
    __syncthreads();  // drains prefetch vmcnt; frees read slots for next ring pass
  }

  // epilogue: O[q][d] / l
  const float linv = 1.0f / l_run;  // valid for q = l31
#pragma unroll
  for (int r = 0; r < 16; ++r) {
    const int qr = (r & 3) + 8 * (r >> 2) + 4 * g;
    const float lv = __shfl(linv, (lane & 32) | qr, 64);
    const int trow = q0 + qr;
    const size_t orow = ((size_t)bb * TT + trow) * 512 + hh * 64 + l31;
    o[orow]      = f2b(oa0[r] * lv);
    o[orow + 32] = f2b(oa1[r] * lv);
  }
}

extern "C" void kernel_launch(void* const* d_in, const int* in_sizes, int n_in,
                              void* d_out, int out_size, void* d_ws, size_t ws_size,
                              hipStream_t stream) {
  (void)in_sizes; (void)n_in; (void)out_size; (void)ws_size;
  const float* x = (const float*)d_in[0];
  const unsigned char* mask = (const unsigned char*)d_in[1];
  const float* ln_w = (const float*)d_in[2];
  const float* ln_b = (const float*)d_in[3];
  const float* w_qkv = (const float*)d_in[4];
  const float* b_qkv = (const float*)d_in[5];
  const float* w_o = (const float*)d_in[6];
  const float* b_o = (const float*)d_in[7];
  float* out = (float*)d_out;

  char* ws = (char*)d_ws;
  short* h_buf = (short*)(ws);                 // 16384*512 bf16 = 16 MB; reused as attn_out
  short* wqkvT = (short*)(ws + 16777216);      // 1536*512 bf16
  short* woT   = (short*)(ws + 18350080);      // 512*512 bf16
  short* q_ws  = (short*)(ws + 18874368);      // [64][2048][64] bf16
  short* k_ws  = (short*)(ws + 35651584);      // [64][2048][64] bf16
  short* vt_ws = (short*)(ws + 52428800);      // [64][64][2048] bf16
  float2* tab  = (float2*)(ws + 69206016);     // [2048][32] float2 = 512 KB

  hipLaunchKernelGGL(prepln_kernel, dim3(8704), dim3(256), 0, stream,
                     x, ln_w, ln_b, h_buf, w_qkv, wqkvT, w_o, woT, tab);
  hipLaunchKernelGGL((gemm128_kernel<0>), dim3(128, 12), dim3(256), 0, stream,
                     h_buf, wqkvT, b_qkv, tab, (void*)q_ws, (void*)k_ws, (void*)vt_ws);
  hipLaunchKernelGGL(attn_kernel, dim3(512), dim3(512), 0, stream,
                     q_ws, k_ws, vt_ws, mask, h_buf);
  hipLaunchKernelGGL((gemm128_kernel<1>), dim3(128, 4), dim3(256), 0, stream,
                     h_buf, woT, b_o, tab, (void*)out, nullptr, nullptr);
}

// Round 14
// 148.589 us; speedup vs baseline: 1.2097x; 1.2097x over previous
//
#include <hip/hip_runtime.h>
#include <hip/hip_bf16.h>

#define TT 2048

typedef __attribute__((ext_vector_type(8))) short bf16x8;
typedef __attribute__((ext_vector_type(4))) float f32x4;
typedef __attribute__((ext_vector_type(16))) float f32x16;
typedef __attribute__((ext_vector_type(2))) int i32x2;

__device__ __forceinline__ short f2b(float f) {
  union { float f; unsigned u; } a; a.f = f;
  unsigned r = a.u + 0x7fffu + ((a.u >> 16) & 1u);
  return (short)(r >> 16);
}
__device__ __forceinline__ unsigned cvtpk(float lo, float hi) {
  unsigned r;
  asm("v_cvt_pk_bf16_f32 %0, %1, %2" : "=v"(r) : "v"(lo), "v"(hi));
  return r;
}
__device__ __forceinline__ float max3f(float a, float b, float c) {
  float d;
  asm("v_max3_f32 %0, %1, %2, %3" : "=v"(d) : "v"(a), "v"(b), "v"(c));
  return d;
}
__device__ __forceinline__ float ex2(float x) {
#if __has_builtin(__builtin_amdgcn_exp2f)
  return __builtin_amdgcn_exp2f(x);
#else
  return exp2f(x);
#endif
}
// async global->LDS, 16B per lane; lds dest = wave-uniform base + lane*16
__device__ __forceinline__ void gll16(const void* g, void* l) {
  __builtin_amdgcn_global_load_lds(
      (const __attribute__((address_space(1))) unsigned int*)g,
      (__attribute__((address_space(3))) unsigned int*)l, 16, 0, 0);
}
// exchange high-32 lanes of a with low-32 lanes of b
__device__ __forceinline__ void swap_halves(unsigned &a, unsigned &b, bool hi) {
#if __has_builtin(__builtin_amdgcn_permlane32_swap)
  i32x2 r = __builtin_amdgcn_permlane32_swap((int)a, (int)b, false, false);
  a = (unsigned)r[0]; b = (unsigned)r[1];
#else
  unsigned as = (unsigned)__shfl_xor((int)a, 32);
  unsigned bs = (unsigned)__shfl_xor((int)b, 32);
  unsigned na = hi ? bs : a;
  unsigned nb = hi ? b : as;
  a = na; b = nb;
#endif
}

// 16 f32 P-values (one 32-row S^T fragment) -> two PV A-frags
__device__ __forceinline__ void p_to_frags(const f32x16 p, bool hi, bf16x8* f0, bf16x8* f1) {
  unsigned A[4][2];
#pragma unroll
  for (int u = 0; u < 4; ++u)
#pragma unroll
    for (int c = 0; c < 2; ++c)
      A[u][c] = cvtpk(p[4 * u + 2 * c], p[4 * u + 2 * c + 1]);
  swap_halves(A[0][0], A[1][0], hi);
  swap_halves(A[0][1], A[1][1], hi);
  swap_halves(A[2][0], A[3][0], hi);
  swap_halves(A[2][1], A[3][1], hi);
  union { unsigned u[4]; bf16x8 v; } r0, r1;
  r0.u[0] = A[0][0]; r0.u[1] = A[0][1]; r0.u[2] = A[1][0]; r0.u[3] = A[1][1];
  r1.u[0] = A[2][0]; r1.u[1] = A[2][1]; r1.u[2] = A[3][0]; r1.u[3] = A[3][1];
  *f0 = r0.v; *f1 = r1.v;
}

// swizzled LDS access, 128B rows: byte col ^ ((row&7)<<4)
__device__ __forceinline__ bf16x8 lds16(const short* base, int row, int cb) {
  return *reinterpret_cast<const bf16x8*>(
      reinterpret_cast<const char*>(base) + row * 128 + (cb ^ ((row & 7) << 4)));
}

// fused: LayerNorm (blocks 0..8191) + weight transpose-cast (8192..8447) +
// RoPE table (8448..8703)
__global__ __launch_bounds__(256) void prepln_kernel(const float* __restrict__ x,
                                                     const float* __restrict__ lnw,
                                                     const float* __restrict__ lnb,
                                                     short* __restrict__ h,
                                                     const float* __restrict__ w_qkv,
                                                     short* __restrict__ wqkvT,
                                                     const float* __restrict__ w_o,
                                                     short* __restrict__ woT,
                                                     float2* __restrict__ tab) {
  __shared__ float t[64][65];
  const int id = blockIdx.x;
  const int tid = threadIdx.x;
  if (id < 8192) {
    // LayerNorm: 2 rows/block, float4 loads
    const int row = id * 2 + (tid >> 7);
    const int c = tid & 127;
    const float4 v = *reinterpret_cast<const float4*>(x + (size_t)row * 512 + c * 4);
    float s = (v.x + v.y) + (v.z + v.w);
    float sq = (v.x * v.x + v.y * v.y) + (v.z * v.z + v.w * v.w);
    for (int off = 1; off < 64; off <<= 1) { s += __shfl_xor(s, off); sq += __shfl_xor(sq, off); }
    __shared__ float red[8];
    const int wv = tid >> 6;
    if ((tid & 63) == 0) { red[wv] = s; red[wv + 4] = sq; }
    __syncthreads();
    const int rb = (tid >> 7) ? 2 : 0;
    s = red[rb] + red[rb + 1];
    sq = red[rb + 4] + red[rb + 5];
    const float mu = s * (1.0f / 512.0f);
    const float var = sq * (1.0f / 512.0f) - mu * mu;
    const float inv = rsqrtf(var + 1e-5f);
    const float4 wv4 = *reinterpret_cast<const float4*>(lnw + c * 4);
    const float4 bv4 = *reinterpret_cast<const float4*>(lnb + c * 4);
    const float h0 = (v.x - mu) * inv * wv4.x + bv4.x;
    const float h1 = (v.y - mu) * inv * wv4.y + bv4.y;
    const float h2 = (v.z - mu) * inv * wv4.z + bv4.z;
    const float h3 = (v.w - mu) * inv * wv4.w + bv4.w;
    uint2 u;
    u.x = (unsigned)(unsigned short)f2b(h0) | ((unsigned)(unsigned short)f2b(h1) << 16);
    u.y = (unsigned)(unsigned short)f2b(h2) | ((unsigned)(unsigned short)f2b(h3) << 16);
    *reinterpret_cast<uint2*>(h + (size_t)row * 512 + c * 4) = u;
  } else if (id < 8448) {
    const int id2 = id - 8192;
    const float* src; short* dst; int N, n0, k0;
    if (id2 < 192) { src = w_qkv; dst = wqkvT; N = 1536; n0 = (id2 % 24) * 64; k0 = (id2 / 24) * 64; }
    else { const int i2 = id2 - 192; src = w_o; dst = woT; N = 512; n0 = (i2 & 7) * 64; k0 = (i2 >> 3) * 64; }
    const int c = tid & 63, r4 = tid >> 6;
#pragma unroll
    for (int i = 0; i < 16; ++i) {
      const int r = i * 4 + r4;
      t[r][c] = src[(size_t)(k0 + r) * N + n0 + c];
    }
    __syncthreads();
#pragma unroll
    for (int i = 0; i < 16; ++i) {
      const int r = i * 4 + r4;
      dst[(size_t)(n0 + r) * 512 + k0 + c] = f2b(t[c][r]);
    }
  } else {
    const int idx = (id - 8448) * 256 + tid;  // 65536
    const int i = idx & 31, tt = idx >> 5;
    const float inv_freq = __expf(-(float)i * (9.210340371976184f / 32.0f));
    float sv, cv;
    sincosf((float)tt * inv_freq, &sv, &cv);
    tab[idx] = make_float2(cv, sv);
  }
}

// 128x128 tile GEMM via global_load_lds, both-sides-swizzled LDS [128][64],
// T4 pipeline: counted vmcnt + raw barriers (no vmcnt(0) drain in loop).
// A[M][512] bf16 row-major, Bt[N][512] bf16 (B transposed).
// EPI=0: bias + fused RoPE, scatter q/k [bh][t][64], v^T [bh][d][t]
// EPI=1: out[row][col] = acc + bias (f32)
template <int EPI>
__global__ __launch_bounds__(256) void gemm128_kernel(const short* __restrict__ A,
                                                      const short* __restrict__ Bt,
                                                      const float* __restrict__ bias,
                                                      const float2* __restrict__ tab,
                                                      void* __restrict__ o0,
                                                      void* __restrict__ o1,
                                                      void* __restrict__ o2) {
  __shared__ short As[2][128 * 64];
  __shared__ short Bs[2][128 * 64];
  const int tid = threadIdx.x;
  const int lane = tid & 63, wave = tid >> 6;
  const int lr = lane & 15, lg = lane >> 4;
  const int wm = wave >> 1, wn = wave & 1;
  const int m0 = blockIdx.x * 128, n0 = blockIdx.y * 128;

  const int swz_col = ((lane & 7) ^ ((lane >> 3) & 7)) * 8;
  const short* Ag = A + (size_t)(m0 + wave * 32 + (lane >> 3)) * 512 + swz_col;
  const short* Bg = Bt + (size_t)(n0 + wave * 32 + (lane >> 3)) * 512 + swz_col;

  f32x4 acc[4][4] = {};

  auto stage = [&](int kk, int buf) {
#pragma unroll
    for (int i = 0; i < 4; ++i) {
      gll16(Ag + (size_t)i * 8 * 512 + kk * 64, &As[buf][(wave * 32 + i * 8) * 64]);
      gll16(Bg + (size_t)i * 8 * 512 + kk * 64, &Bs[buf][(wave * 32 + i * 8) * 64]);
    }
  };
  auto compute = [&](int buf) {
#pragma unroll
    for (int ks = 0; ks < 2; ++ks) {
      bf16x8 af[4], bfr[4];
#pragma unroll
      for (int m = 0; m < 4; ++m)
        af[m] = lds16(As[buf], wm * 64 + m * 16 + lr, ks * 64 + lg * 16);
#pragma unroll
      for (int n = 0; n < 4; ++n)
        bfr[n] = lds16(Bs[buf], wn * 64 + n * 16 + lr, ks * 64 + lg * 16);
#pragma unroll
      for (int m = 0; m < 4; ++m)
#pragma unroll
        for (int n = 0; n < 4; ++n)
          acc[m][n] = __builtin_amdgcn_mfma_f32_16x16x32_bf16(af[m], bfr[n], acc[m][n], 0, 0, 0);
    }
  };

  stage(0, 0);
  for (int kk = 0; kk < 7; ++kk) {
    stage(kk + 1, (kk + 1) & 1);
    // wait only tile kk's 8 glls (kk+1's 8 stay in flight across the barrier)
    asm volatile("s_waitcnt vmcnt(8)" ::: "memory");
    __builtin_amdgcn_s_barrier();
    __builtin_amdgcn_sched_barrier(0);
    compute(kk & 1);
    __builtin_amdgcn_s_barrier();  // WAR: all waves done reading buf kk&1
  }
  asm volatile("s_waitcnt vmcnt(0)" ::: "memory");
  __builtin_amdgcn_s_barrier();
  __builtin_amdgcn_sched_barrier(0);
  compute(1);  // tile 7

  if (EPI == 0) {
    const int base = n0 + wn * 64;             // wave-uniform head window
    const int which = base >> 9;               // 0=q 1=k 2=v
    const int hh = (base & 511) >> 6;
    short* qp = (short*)o0; short* kp = (short*)o1; short* vtp = (short*)o2;
    if (which < 2) {
      const float b0 = bias[base + lr], b1 = bias[base + 16 + lr];
      const float b2 = bias[base + 32 + lr], b3 = bias[base + 48 + lr];
      const float QS = 0.125f * 1.4426950408889634f;  // 1/sqrt(dk) * log2(e), q only
#pragma unroll
      for (int m = 0; m < 4; ++m) {
        const int rowb = m0 + wm * 64 + m * 16 + lg * 4;
#pragma unroll
        for (int j = 0; j < 4; ++j) {
          const int t = (rowb + j) & 2047;
          const int bh = ((rowb + j) >> 11) * 8 + hh;
          float v0 = acc[m][0][j] + b0;
          float v1 = acc[m][1][j] + b1;
          float v2 = acc[m][2][j] + b2;
          float v3 = acc[m][3][j] + b3;
          const float2 cs0 = tab[t * 32 + lr];
          const float2 cs1 = tab[t * 32 + 16 + lr];
          float r0 = v0 * cs0.x - v2 * cs0.y;
          float r2 = v2 * cs0.x + v0 * cs0.y;
          float r1 = v1 * cs1.x - v3 * cs1.y;
          float r3 = v3 * cs1.x + v1 * cs1.y;
          if (which == 0) { r0 *= QS; r1 *= QS; r2 *= QS; r3 *= QS; }
          short* dst = (which == 0 ? qp : kp) + ((size_t)bh * TT + t) * 64;
          dst[lr] = f2b(r0); dst[16 + lr] = f2b(r1);
          dst[32 + lr] = f2b(r2); dst[48 + lr] = f2b(r3);
        }
      }
    } else {
      // V^T path: j-quad = 4 consecutive t at fixed d -> one 8B packed store
      // (lane mapping unchanged vs r12; only per-lane packing added)
      const size_t bh64 = (size_t)((m0 >> 11) * 8 + hh) * 64;
      const float b0 = bias[base + lr], b1 = bias[base + 16 + lr];
      const float b2 = bias[base + 32 + lr], b3 = bias[base + 48 + lr];
      const float bv[4] = { b0, b1, b2, b3 };
#pragma unroll
      for (int m = 0; m < 4; ++m) {
        const int t0 = (m0 + wm * 64 + m * 16 + lg * 4) & 2047;
#pragma unroll
        for (int n = 0; n < 4; ++n) {
          const int d = n * 16 + lr;
          uint2 pv;
          pv.x = cvtpk(acc[m][n][0] + bv[n], acc[m][n][1] + bv[n]);
          pv.y = cvtpk(acc[m][n][2] + bv[n], acc[m][n][3] + bv[n]);
          *reinterpret_cast<uint2*>(vtp + (bh64 + d) * TT + t0) = pv;
        }
      }
    }
  } else {
#pragma unroll
    for (int m = 0; m < 4; ++m)
#pragma unroll
      for (int n = 0; n < 4; ++n)
#pragma unroll
        for (int j = 0; j < 4; ++j) {
          const int row = m0 + wm * 64 + m * 16 + lg * 4 + j;
          const int col = n0 + wn * 64 + n * 16 + lr;
          ((float*)o0)[(size_t)row * 512 + col] = acc[m][n][j] + bias[col];
        }
  }
}

// Flash attention, swapped-QK^T 32x32x16, exp2 softmax, gll-staged pipeline.
// 8 waves x 32 q-rows = 256 q-rows/block. Depth-2: 2 K-tiles per barrier,
// 4-deep K/V LDS rings. [round-11/12 proven structure — unchanged]
__global__ __launch_bounds__(512) void attn_kernel(const short* __restrict__ q,
                                                   const short* __restrict__ k,
                                                   const short* __restrict__ vt,
                                                   const unsigned char* __restrict__ mask,
                                                   short* __restrict__ o) {
  __shared__ short Ks[4][64 * 64];
  __shared__ short Vs[4][64 * 64];
  __shared__ float psc[8][32];
  const int tid = threadIdx.x;
  const int lane = tid & 63, wave = tid >> 6;  // wave 0..7
  const int l31 = lane & 31, g = lane >> 5;
  const bool hi = (g != 0);
  // bijective XCD swizzle: 512 blocks, 8 XCDs -> 8 q-tiles of one bh per XCD
  const int nb = (blockIdx.x & 7) * 64 + (blockIdx.x >> 3);
  const int bh = nb >> 3, qt = nb & 7;
  const int bb = bh >> 3, hh = bh & 7;
  const int q0 = qt * 256 + wave * 32;
  const size_t bhT = (size_t)bh * TT;
  const unsigned char* maskb = mask + (size_t)bb * TT;

  // whole-row mask flag (hoisted)
  unsigned mor = 0;
  const unsigned* mw = (const unsigned*)maskb;
#pragma unroll
  for (int i = 0; i < 8; ++i) mor |= mw[lane + 64 * i];
  const bool masked = __any((int)(mor != 0));

  // Q as B-operand frags
  bf16x8 qf[4];
#pragma unroll
  for (int ds = 0; ds < 4; ++ds)
    qf[ds] = *reinterpret_cast<const bf16x8*>(q + (bhT + q0 + l31) * 64 + ds * 16 + g * 8);

  f32x16 oa0 = {}, oa1 = {};
  float m_run = 0.0f, l_run = 0.0f;

  // gll staging: wave w stages K rows [w*8, +8) and V d-rows [w*8, +8)
  const int swz_col = ((lane & 7) ^ ((lane >> 3) & 7)) * 8;
  const int r0 = wave * 8;
  const short* kg0 = k + (bhT + r0 + (lane >> 3)) * 64 + swz_col;
  const short* vg0 = vt + ((size_t)bh * 64 + r0 + (lane >> 3)) * TT + swz_col;

  auto stage = [&](int kt, int buf) {
    gll16(kg0 + (size_t)kt * 4096, &Ks[buf][r0 * 64]);
    gll16(vg0 + (size_t)kt * 64,   &Vs[buf][r0 * 64]);
  };

  auto tile = [&](int kt, const short* Kc, const short* Vc) {
    // S^T = K Q^T
    f32x16 s0 = {}, s1 = {};
    __builtin_amdgcn_s_setprio(1);
#pragma unroll
    for (int ds = 0; ds < 4; ++ds) {
      const int cb = ds * 32 + g * 16;
      const bf16x8 ka0 = lds16(Kc, l31, cb);
      const bf16x8 ka1 = lds16(Kc, 32 + l31, cb);
      s0 = __builtin_amdgcn_mfma_f32_32x32x16_bf16(ka0, qf[ds], s0, 0, 0, 0);
      s1 = __builtin_amdgcn_mfma_f32_32x32x16_bf16(ka1, qf[ds], s1, 0, 0, 0);
    }
    __builtin_amdgcn_s_setprio(0);

    if (masked) {
#pragma unroll
      for (int r = 0; r < 16; ++r) {
        const int kk = (r & 3) + 8 * (r >> 2) + 4 * g;
        if (maskb[kt * 64 + kk]) s0[r] += -1e30f;
        if (maskb[kt * 64 + 32 + kk]) s1[r] += -1e30f;
      }
    }

    // row max over 64 keys: max3 tree + cross-half
    float b8[8];
#pragma unroll
    for (int i = 0; i < 8; ++i) b8[i] = max3f(s0[i], s0[i + 8], s1[i]);
    float c4[4];
#pragma unroll
    for (int i = 0; i < 4; ++i) c4[i] = fmaxf(s1[8 + i], s1[12 + i]);
    const float d0 = max3f(b8[0], b8[1], b8[2]);
    const float d1 = max3f(b8[3], b8[4], b8[5]);
    const float d2 = max3f(b8[6], b8[7], c4[0]);
    const float d3 = max3f(c4[1], c4[2], c4[3]);
    const float mx = fmaxf(max3f(d0, d1, d2), d3);
    const float pmax = fmaxf(mx, __shfl_xor(mx, 32));

    if (kt == 0) {
      m_run = pmax;
    } else if (!__all((int)(pmax - m_run <= 8.0f))) {
      const float nm = fmaxf(m_run, pmax);
      const float sc = ex2(m_run - nm);
      m_run = nm;
      l_run *= sc;
      if (lane < 32) psc[wave][l31] = sc;
      asm volatile("s_waitcnt lgkmcnt(0)" ::: "memory");
#pragma unroll
      for (int r = 0; r < 16; ++r) {
        const float s = psc[wave][(r & 3) + 8 * (r >> 2) + 4 * g];
        oa0[r] *= s; oa1[r] *= s;
      }
    }

    // P = exp2(S - m) in place
#pragma unroll
    for (int i = 0; i < 16; ++i) { s0[i] = ex2(s0[i] - m_run); s1[i] = ex2(s1[i] - m_run); }

    // row sum (pairwise tree)
    float a8[8];
#pragma unroll
    for (int i = 0; i < 8; ++i) a8[i] = (s0[i] + s0[i + 8]) + (s1[i] + s1[i + 8]);
    const float e0 = (a8[0] + a8[1]) + (a8[2] + a8[3]);
    const float e1 = (a8[4] + a8[5]) + (a8[6] + a8[7]);
    const float rsum = e0 + e1;
    l_run += rsum + __shfl_xor(rsum, 32);

    // P -> bf16 A-frags in-register
    bf16x8 pa[4];
    p_to_frags(s0, hi, &pa[0], &pa[1]);
    p_to_frags(s1, hi, &pa[2], &pa[3]);

    // O += P V
    __builtin_amdgcn_s_setprio(1);
#pragma unroll
    for (int ks = 0; ks < 4; ++ks) {
      const int cb = ks * 32 + g * 16;
      const bf16x8 vb0 = lds16(Vc, l31, cb);
      const bf16x8 vb1 = lds16(Vc, 32 + l31, cb);
      oa0 = __builtin_amdgcn_mfma_f32_32x32x16_bf16(pa[ks], vb0, oa0, 0, 0, 0);
      oa1 = __builtin_amdgcn_mfma_f32_32x32x16_bf16(pa[ks], vb1, oa1, 0, 0, 0);
    }
    __builtin_amdgcn_s_setprio(0);
  };

  // prologue: stage tiles 0 and 1
  stage(0, 0);
  stage(1, 1);
  __syncthreads();

  for (int kt = 0; kt < TT / 64; kt += 2) {
    if (kt + 2 < TT / 64) stage(kt + 2, (kt + 2) & 3);
    if (kt + 3 < TT / 64) stage(kt + 3, (kt + 3) & 3);
    tile(kt,     Ks[kt & 3],       Vs[kt & 3]);
    tile(kt + 1, Ks[(kt + 1) & 3], Vs[(kt + 1) & 3]);
    __syncthreads();  // drains prefetch vmcnt; frees read slots for next ring pass
  }

  // epilogue: O[q][d] / l
  const float linv = 1.0f / l_run;  // valid for q = l31
#pragma unroll
  for (int r = 0; r < 16; ++r) {
    const int qr = (r & 3) + 8 * (r >> 2) + 4 * g;
    const float lv = __shfl(linv, (lane & 32) | qr, 64);
    const int trow = q0 + qr;
    const size_t orow = ((size_t)bb * TT + trow) * 512 + hh * 64 + l31;
    o[orow]      = f2b(oa0[r] * lv);
    o[orow + 32] = f2b(oa1[r] * lv);
  }
}

extern "C" void kernel_launch(void* const* d_in, const int* in_sizes, int n_in,
                              void* d_out, int out_size, void* d_ws, size_t ws_size,
                              hipStream_t stream) {
  (void)in_sizes; (void)n_in; (void)out_size; (void)ws_size;
  const float* x = (const float*)d_in[0];
  const unsigned char* mask = (const unsigned char*)d_in[1];
  const float* ln_w = (const float*)d_in[2];
  const float* ln_b = (const float*)d_in[3];
  const float* w_qkv = (const float*)d_in[4];
  const float* b_qkv = (const float*)d_in[5];
  const float* w_o = (const float*)d_in[6];
  const float* b_o = (const float*)d_in[7];
  float* out = (float*)d_out;

  char* ws = (char*)d_ws;
  short* h_buf = (short*)(ws);                 // 16384*512 bf16 = 16 MB; reused as attn_out
  short* wqkvT = (short*)(ws + 16777216);      // 1536*512 bf16
  short* woT   = (short*)(ws + 18350080);      // 512*512 bf16
  short* q_ws  = (short*)(ws + 18874368);      // [64][2048][64] bf16
  short* k_ws  = (short*)(ws + 35651584);      // [64][2048][64] bf16
  short* vt_ws = (short*)(ws + 52428800);      // [64][64][2048] bf16
  float2* tab  = (float2*)(ws + 69206016);     // [2048][32] float2 = 512 KB

  hipLaunchKernelGGL(prepln_kernel, dim3(8704), dim3(256), 0, stream,
                     x, ln_w, ln_b, h_buf, w_qkv, wqkvT, w_o, woT, tab);
  hipLaunchKernelGGL((gemm128_kernel<0>), dim3(128, 12), dim3(256), 0, stream,
                     h_buf, wqkvT, b_qkv, tab, (void*)q_ws, (void*)k_ws, (void*)vt_ws);
  hipLaunchKernelGGL(attn_kernel, dim3(512), dim3(512), 0, stream,
                     q_ws, k_ws, vt_ws, mask, h_buf);
  hipLaunchKernelGGL((gemm128_kernel<1>), dim3(128, 4), dim3(256), 0, stream,
                     h_buf, woT, b_o, tab, (void*)out, nullptr, nullptr);
}